// Round 7
// baseline (523.109 us; speedup 1.0000x reference)
//
#include <hip/hip_runtime.h>

#define NROWS 65536
#define DIN   784
#define NF    10
#define NL    62
#define NSTAT 65
#define NB    1024          // passA grid = partials per stat
#define NT    49            // K tiles of 16: 49*16 = 784 exact

// d_ws byte layout
#define STATSF_OFF_B 0       // 110 f32
#define PART_OFF_B   512     // 65*1024 f32, [stat][block], 16B-aligned

// direct global->LDS, 16B per lane (LDS dest = uniform base + lane*16)
__device__ __forceinline__ void gload_lds16(const float* g, float* l) {
  __builtin_amdgcn_global_load_lds(
      (const __attribute__((address_space(1))) void*)g,
      (__attribute__((address_space(3))) void*)l, 16, 0, 0);
}

// ---------------- pass A: z0 = x@W0^T + b0, async-staged ----------------
// 1 wave / 64 rows per block; dbuf 64x16 LDS tiles; counted vmcnt pipeline.
__global__ __launch_bounds__(64, 4) void passA(const float* __restrict__ x,
                                               const float* __restrict__ W0,
                                               const float* __restrict__ b0,
                                               float* __restrict__ zout,
                                               float* __restrict__ partials) {
  __shared__ __align__(16) float xs[2][1024];   // 2 x 4 KB tiles, swizzled
  const int lane = threadIdx.x;
  const int rowbase = blockIdx.x * 64;
  const float* xb = x + (size_t)rowbase * DIN;

  // staging map: instr q, lane l writes LDS floats [q*256+4l, +4) = row 16q+(l>>2), slot l&3.
  // slot s of row r holds col-block i = s ^ ((r>>1)&3); (r>>1)&3 == (l>>3)&3 (q-independent).
  // -> bank-quad (4*(r&1) + slot) mod 8 covers all 8 quads over 8 rows: optimal 8 lanes/quad.
  const int srow = lane >> 2;
  const int scol = ((lane & 3) ^ ((lane >> 3) & 3)) << 2;
  const size_t sidx = (size_t)srow * DIN + scol;

#define STAGE(t, b)                                                            \
  do {                                                                         \
    asm volatile("s_waitcnt lgkmcnt(0)" ::: "memory"); /* WAR: prior ds_reads retired */ \
    const float* s_ = xb + (size_t)(t) * 16 + sidx;                            \
    gload_lds16(s_ + 0 * 16 * DIN, &xs[b][0 * 256]);                           \
    gload_lds16(s_ + 1 * 16 * DIN, &xs[b][1 * 256]);                           \
    gload_lds16(s_ + 2 * 16 * DIN, &xs[b][2 * 256]);                           \
    gload_lds16(s_ + 3 * 16 * DIN, &xs[b][3 * 256]);                           \
  } while (0)

  float acc[NF];
#pragma unroll
  for (int j = 0; j < NF; ++j) acc[j] = b0[j];    // uniform -> s_load

  // read-side: lane r, col-block i lives at float idx r*16 + 4*(i ^ ((r>>1)&3))
  const int rbase = lane << 4;
  const int rx = (lane >> 1) & 3;

#define COMP(t, b)                                                             \
  do {                                                                         \
    _Pragma("unroll") for (int i = 0; i < 4; ++i) {                            \
      float4 v = *(const float4*)(&xs[b][rbase + (((i) ^ rx) << 2)]);          \
      const float* wk = W0 + (t) * 16 + (i << 2);   /* uniform -> s_load */    \
      _Pragma("unroll") for (int j = 0; j < NF; ++j) {                         \
        acc[j] = fmaf(v.x, wk[j * DIN + 0], acc[j]);                           \
        acc[j] = fmaf(v.y, wk[j * DIN + 1], acc[j]);                           \
        acc[j] = fmaf(v.z, wk[j * DIN + 2], acc[j]);                           \
        acc[j] = fmaf(v.w, wk[j * DIN + 3], acc[j]);                           \
      }                                                                        \
    }                                                                          \
  } while (0)

  STAGE(0, 0);
  for (int t = 0; t < NT - 1; ++t) {
    STAGE(t + 1, (t + 1) & 1);                     // next tile's 4 loads stay in flight
    asm volatile("s_waitcnt vmcnt(4)" ::: "memory");  // tile t resident in LDS
    __builtin_amdgcn_sched_barrier(0);             // don't hoist ds_read above the wait
    COMP(t, t & 1);
  }
  asm volatile("s_waitcnt vmcnt(0)" ::: "memory");
  __builtin_amdgcn_sched_barrier(0);
  COMP(NT - 1, 0);                                 // (NT-1)&1 == 0
#undef STAGE
#undef COMP

  // z0 write (40B contiguous per lane)
  {
    float* zr = zout + (size_t)(rowbase + lane) * NF;
#pragma unroll
    for (int j = 0; j < NF; j += 2) *(float2*)(zr + j) = make_float2(acc[j], acc[j + 1]);
  }

  // 65 moments: single-wave butterfly reductions (independent chains -> ILP)
#define RED(s)                                                                 \
  do {                                                                         \
    _Pragma("unroll") for (int m_ = 1; m_ < 64; m_ <<= 1) s += __shfl_xor(s, m_, 64); \
  } while (0)
  {
    int kk = 0;
#pragma unroll
    for (int i = 0; i < NF; ++i) {
      float s = acc[i];
      RED(s);
      if (lane == (kk & 63)) partials[kk * NB + blockIdx.x] = s;
      ++kk;
    }
#pragma unroll
    for (int i = 0; i < NF; ++i) {
#pragma unroll
      for (int j = i; j < NF; ++j) {
        float s = acc[i] * acc[j];
        RED(s);
        if (lane == (kk & 63)) partials[kk * NB + blockIdx.x] = s;
        ++kk;
      }
    }
  }
#undef RED
}

// ---------------- pass B: 2-wave pipelined analytic BN recursion ----------------
// wave0: f64 Cov spine (V -> LDS transpose -> Cz -> scales); wave1: f32 M/dv chain.
// One barrier per layer; scales double-buffered: f64 svld (wave0), f32 svl (wave1).
__global__ __launch_bounds__(128, 1) void passB(const float* __restrict__ partials,
                                                const float* __restrict__ Ws,
                                                const float* __restrict__ g0,
                                                const float* __restrict__ gs,
                                                const float* __restrict__ betas,
                                                const float* __restrict__ Wfin,
                                                const float* __restrict__ bfin,
                                                float* __restrict__ statsf) {
  __shared__ double WLd[NL * 100];    // 49.6 KB: f64 weights (wave0 spine)
  __shared__ float  WL[NL * 100];     // 24.8 KB: f32 weights (wave1)
  __shared__ float  gsl[NL * NF];
  __shared__ double Sd[NSTAT];
  __shared__ double tbd[NF * NF];     // wave0-private transpose (within-wave ordered)
  __shared__ double svld[2 * NF];     // f64 scale mailbox (wave0-private)
  __shared__ float  svl[2 * NF];      // f32 scale mailbox (wave0 -> wave1)
  const int tid = threadIdx.x;
  const int lane = tid & 63;
  const int wv = __builtin_amdgcn_readfirstlane(tid >> 6);
  const int il = lane < NF ? lane : NF - 1;
  const bool owner = lane < NF;

  for (int i = tid; i < NL * 100; i += 128) {
    float w = Ws[i]; WL[i] = w; WLd[i] = (double)w;
  }
  for (int i = tid; i < NL * NF; i += 128) gsl[i] = gs[i];

  // phase 0: coalesced stat reduction (wave per stat-set, lane-strided, f64)
  {
    const int k0 = (wv == 0) ? 0 : 33, k1 = (wv == 0) ? 33 : NSTAT;
    for (int k = k0; k < k1; ++k) {
      const float* pr = partials + (size_t)k * NB;
      double s = 0.0;
#pragma unroll
      for (int i = 0; i < NB / 64; ++i) s += (double)pr[i * 64 + lane];
#pragma unroll
      for (int m = 1; m < 64; m <<= 1) s += __shfl_xor(s, m, 64);
      if (lane == 0) Sd[k] = s;
    }
  }
  __syncthreads();

  const double invN = 1.0 / (double)NROWS;
  if (wv == 0) {                      // BN0 scales (f64 bootstrap)
    const int idxd = NF + il * NF - (il * (il - 1)) / 2;
    double mu_own = Sd[il] * invN;
    double var_own = Sd[idxd] * invN - mu_own * mu_own;
    double s0 = (double)g0[il] / sqrt(var_own + 1e-5);
    if (owner) { svld[il] = s0; svl[il] = (float)s0; }   // scale-set 0 -> slot 0
  }
  __syncthreads();

  // per-wave state
  double CovRd[NF];                   // wave0: row il of scaled Cov (f64)
  float Mrow[NF], dvv[NF];            // wave1: row il of A, replicated dv (f32)
  if (wv == 0) {
    double s_own = svld[il];
    double mu_own = Sd[il] * invN;
#pragma unroll
    for (int j = 0; j < NF; ++j) {
      int a_ = il < j ? il : j, b_ = il < j ? j : il;
      int idx = NF + a_ * NF - (a_ * (a_ - 1)) / 2 + (b_ - a_);
      double cov = Sd[idx] * invN - mu_own * (Sd[j] * invN);
      CovRd[j] = cov * s_own * svld[j];
    }
  } else {
#pragma unroll
    for (int j = 0; j < NF; ++j) {
      float sj = svl[j];
      Mrow[j] = (il == j) ? sj : 0.f;
      dvv[j] = -(float)(Sd[j] * invN) * sj;   // dv0 = -s0 .* mu0
    }
  }

  double CzRd[NF];
  float Pt[NF], Dt[NF], s2f = 0.f;
  for (int k = 0; k < NL; ++k) {
    const int slot = ((k + 1) & 1) * NF;
    if (wv == 0) {
      const double* Wd = &WLd[k * 100];
      // V = Cov * W^T (row-local, f64), stage to tbd
      double VR[NF];
#pragma unroll
      for (int l = 0; l < NF; ++l) {
        double t = 0.0;
#pragma unroll
        for (int m = 0; m < NF; ++m) t = fma(CovRd[m], Wd[l * 10 + m], t);
        VR[l] = t;
      }
      if (owner) {
#pragma unroll
        for (int l = 0; l < NF; ++l) tbd[il * NF + l] = VR[l];
      }
      // within-wave LDS write->read ordered; no barrier needed
      double YR[NF];
#pragma unroll
      for (int l = 0; l < NF; ++l) YR[l] = tbd[l * NF + il];  // V^T row (Cov symmetric)
#pragma unroll
      for (int j = 0; j < NF; ++j) {
        double t = 0.0;
#pragma unroll
        for (int l = 0; l < NF; ++l) t = fma(YR[l], Wd[j * 10 + l], t);
        CzRd[j] = t;                  // row of W Cov W^T
      }
      double cz_own = CzRd[0];
#pragma unroll
      for (int j = 1; j < NF; ++j) cz_own = (il == j) ? CzRd[j] : cz_own;
      s2f = gsl[k * NF + il] / sqrtf((float)cz_own + 1e-5f);  // 1e-7 rel, harmless
      if (owner) { svld[slot + il] = (double)s2f; svl[slot + il] = s2f; }
    } else {
      const float* W = &WL[k * 100];
      // M/dv matmul with W_k (independent of new scales)
#pragma unroll
      for (int j = 0; j < NF; ++j) {
        float t = 0.f, u = 0.f;
#pragma unroll
        for (int l = 0; l < NF; ++l) {
          t = fmaf(Mrow[l], W[j * 10 + l], t);
          u = fmaf(dvv[l], W[j * 10 + l], u);
        }
        Pt[j] = t; Dt[j] = u;
      }
    }
    __syncthreads();                  // publish scale-set k+1
    if (wv == 0) {
      double s2d = (double)s2f;
#pragma unroll
      for (int j = 0; j < NF; ++j) CovRd[j] = CzRd[j] * s2d * svld[slot + j];
    } else {
#pragma unroll
      for (int j = 0; j < NF; ++j) {
        float sj = svl[slot + j];
        Mrow[j] = Pt[j] * sj; dvv[j] = Dt[j] * sj;
      }
    }
  }

  // final fold on wave1: Mf = A * Wf^T ; cf = bf + (dv + beta_last) Wf^T
  if (wv == 1) {
    float cvecf[NF];
#pragma unroll
    for (int j = 0; j < NF; ++j) cvecf[j] = dvv[j] + betas[(NL - 1) * NF + j];
    float Ff[NF], cf[NF];
#pragma unroll
    for (int j = 0; j < NF; ++j) {
      float t = 0.f, u = bfin[j];
#pragma unroll
      for (int l = 0; l < NF; ++l) {
        t = fmaf(Mrow[l], Wfin[j * 10 + l], t);
        u = fmaf(cvecf[l], Wfin[j * 10 + l], u);
      }
      Ff[j] = t; cf[j] = u;
    }
    if (owner) {
#pragma unroll
      for (int j = 0; j < NF; ++j) statsf[il * NF + j] = Ff[j];
    }
    if (lane == 0) {
#pragma unroll
      for (int j = 0; j < NF; ++j) statsf[100 + j] = cf[j];
    }
  }
}

// ---------------- pass C: out = z0 @ M + c (in place) ----------------
__global__ __launch_bounds__(256) void passC(float* __restrict__ z_inout,
                                             const float* __restrict__ statsf) {
  const int r = blockIdx.x * 256 + threadIdx.x;
  float* pz = z_inout + (size_t)r * NF;
  float zr[NF];
#pragma unroll
  for (int j = 0; j < NF; j += 2) {
    float2 v = *(const float2*)(pz + j);
    zr[j] = v.x; zr[j + 1] = v.y;
  }
  float acc2[NF];
#pragma unroll
  for (int j = 0; j < NF; ++j) acc2[j] = statsf[100 + j];
#pragma unroll
  for (int l = 0; l < NF; ++l)
#pragma unroll
    for (int j = 0; j < NF; ++j) acc2[j] = fmaf(zr[l], statsf[l * 10 + j], acc2[j]);
#pragma unroll
  for (int j = 0; j < NF; j += 2) *(float2*)(pz + j) = make_float2(acc2[j], acc2[j + 1]);
}

extern "C" void kernel_launch(void* const* d_in, const int* in_sizes, int n_in,
                              void* d_out, int out_size, void* d_ws, size_t ws_size,
                              hipStream_t stream) {
  const float* x     = (const float*)d_in[0];
  const float* W0    = (const float*)d_in[1];
  const float* b0    = (const float*)d_in[2];
  const float* g0    = (const float*)d_in[3];
  const float* Ws    = (const float*)d_in[5];
  const float* gs    = (const float*)d_in[7];
  const float* betas = (const float*)d_in[8];
  const float* Wfin  = (const float*)d_in[9];
  const float* bfin  = (const float*)d_in[10];
  float* out = (float*)d_out;
  // d_in[4]=beta0, d_in[6]=bs cancel exactly inside the BN algebra (see passB derivation)

  float* statsf   = (float*)((char*)d_ws + STATSF_OFF_B);
  float* partials = (float*)((char*)d_ws + PART_OFF_B);

  passA<<<NB, 64, 0, stream>>>(x, W0, b0, out, partials);
  passB<<<1, 128, 0, stream>>>(partials, Ws, g0, gs, betas, Wfin, bfin, statsf);
  passC<<<256, 256, 0, stream>>>(out, statsf);
}